// Round 5
// baseline (444.301 us; speedup 1.0000x reference)
//
#include <hip/hip_runtime.h>
#include <math.h>

// ws float layout:
//  [0]      E_sum
//  [1]      tr_gp
//  [2..17]  m[16]
//  [18..33] cs[16]
//  [64..2112)   B[16][128]   (atomic-accumulated, zeroed)
//  [2112..4160) P2[16][128]  (written by finalize, no zero needed)

#define WS_ESUM 0
#define WS_TR   1
#define WS_M    2
#define WS_CS   18
#define WS_B    64
#define WS_P2   2112

// ---------------------------------------------------------------- k_assign
// A[n,:] = softmax(F[n,:] @ W^T + b); cs[k] += sum_n A[n,k]
// (R1-verified version: one thread per node)
__global__ __launch_bounds__(256) void k_assign(
    const float* __restrict__ F, const float* __restrict__ W,
    const float* __restrict__ bias, float* __restrict__ A,
    float* __restrict__ cs, int N) {
  __shared__ float Ws[2048];       // fc_w [16][128]
  __shared__ float csred[4][16];
  int t = threadIdx.x;
#pragma unroll
  for (int i = 0; i < 8; i++) Ws[t + 256 * i] = W[t + 256 * i];
  __syncthreads();

  int n = blockIdx.x * 256 + t;
  float a[16];
  if (n < N) {
#pragma unroll
    for (int k = 0; k < 16; k++) a[k] = bias[k];
    const float4* f4 = (const float4*)(F + (size_t)n * 128);
#pragma unroll 4
    for (int i = 0; i < 32; i++) {
      float4 f = f4[i];
#pragma unroll
      for (int k = 0; k < 16; k++) {
        float4 w = *(const float4*)(&Ws[k * 128 + i * 4]);
        a[k] = fmaf(f.x, w.x, a[k]);
        a[k] = fmaf(f.y, w.y, a[k]);
        a[k] = fmaf(f.z, w.z, a[k]);
        a[k] = fmaf(f.w, w.w, a[k]);
      }
    }
    // softmax
    float mx = a[0];
#pragma unroll
    for (int k = 1; k < 16; k++) mx = fmaxf(mx, a[k]);
    float s = 0.f;
#pragma unroll
    for (int k = 0; k < 16; k++) { a[k] = __expf(a[k] - mx); s += a[k]; }
    float inv = 1.0f / s;
#pragma unroll
    for (int k = 0; k < 16; k++) a[k] *= inv;
    float4* o = (float4*)(A + (size_t)n * 16);
    o[0] = make_float4(a[0], a[1], a[2], a[3]);
    o[1] = make_float4(a[4], a[5], a[6], a[7]);
    o[2] = make_float4(a[8], a[9], a[10], a[11]);
    o[3] = make_float4(a[12], a[13], a[14], a[15]);
  } else {
#pragma unroll
    for (int k = 0; k < 16; k++) a[k] = 0.f;
  }

  // cluster sizes: wave butterfly, then cross-wave via LDS, then atomic
#pragma unroll
  for (int k = 0; k < 16; k++) {
    float v = a[k];
    for (int off = 32; off; off >>= 1) v += __shfl_xor(v, off, 64);
    a[k] = v;
  }
  int lane = t & 63, wid = t >> 6;
  if (lane == 0) {
#pragma unroll
    for (int k = 0; k < 16; k++) csred[wid][k] = a[k];
  }
  __syncthreads();
  if (t < 16)
    atomicAdd(&cs[t], csred[0][t] + csred[1][t] + csred[2][t] + csred[3][t]);
}

// ---------------------------------------------------------------- k_edge
// E_sum = sum val;  m[k] = sum val*A[col,k];  tr = sum val*dot(A[row],A[col])
__global__ __launch_bounds__(256) void k_edge(
    const int* __restrict__ row, const int* __restrict__ col,
    const float* __restrict__ val, const float* __restrict__ A,
    float* __restrict__ ws, int E) {
  float eS = 0.f, tr = 0.f;
  float m[16];
#pragma unroll
  for (int i = 0; i < 16; i++) m[i] = 0.f;

  int tid = blockIdx.x * 256 + threadIdx.x;
  int T = gridDim.x * 256;
  for (int e = tid; e < E; e += T) {
    int r = row[e], c = col[e];
    float v = val[e];
    const float4* Ac4 = (const float4*)(A + (size_t)c * 16);
    const float4* Ar4 = (const float4*)(A + (size_t)r * 16);
    float4 c0 = Ac4[0], c1 = Ac4[1], c2 = Ac4[2], c3 = Ac4[3];
    float4 r0 = Ar4[0], r1 = Ar4[1], r2 = Ar4[2], r3 = Ar4[3];
    eS += v;
    m[0]  = fmaf(v, c0.x, m[0]);  m[1]  = fmaf(v, c0.y, m[1]);
    m[2]  = fmaf(v, c0.z, m[2]);  m[3]  = fmaf(v, c0.w, m[3]);
    m[4]  = fmaf(v, c1.x, m[4]);  m[5]  = fmaf(v, c1.y, m[5]);
    m[6]  = fmaf(v, c1.z, m[6]);  m[7]  = fmaf(v, c1.w, m[7]);
    m[8]  = fmaf(v, c2.x, m[8]);  m[9]  = fmaf(v, c2.y, m[9]);
    m[10] = fmaf(v, c2.z, m[10]); m[11] = fmaf(v, c2.w, m[11]);
    m[12] = fmaf(v, c3.x, m[12]); m[13] = fmaf(v, c3.y, m[13]);
    m[14] = fmaf(v, c3.z, m[14]); m[15] = fmaf(v, c3.w, m[15]);
    float d = r0.x * c0.x + r0.y * c0.y + r0.z * c0.z + r0.w * c0.w
            + r1.x * c1.x + r1.y * c1.y + r1.z * c1.z + r1.w * c1.w
            + r2.x * c2.x + r2.y * c2.y + r2.z * c2.z + r2.w * c2.w
            + r3.x * c3.x + r3.y * c3.y + r3.z * c3.z + r3.w * c3.w;
    tr = fmaf(v, d, tr);
  }

  float vals[18];
  vals[0] = eS; vals[1] = tr;
#pragma unroll
  for (int i = 0; i < 16; i++) vals[2 + i] = m[i];
#pragma unroll
  for (int i = 0; i < 18; i++) {
    float v = vals[i];
    for (int off = 32; off; off >>= 1) v += __shfl_xor(v, off, 64);
    vals[i] = v;
  }
  __shared__ float red[4][18];
  int lane = threadIdx.x & 63, wid = threadIdx.x >> 6;
  if (lane == 0) {
#pragma unroll
    for (int i = 0; i < 18; i++) red[wid][i] = vals[i];
  }
  __syncthreads();
  if (threadIdx.x < 18)
    atomicAdd(&ws[threadIdx.x],
              red[0][threadIdx.x] + red[1][threadIdx.x] +
              red[2][threadIdx.x] + red[3][threadIdx.x]);
}

// ---------------------------------------------------------------- k_nodeB
// B[k,c] = sum_n A[n,k] * F[n,c]   (16 x 128)
// thread: q = t&31 (float4 column), sub = t>>5 (node slot 0..7).
// A wave's F loads are one contiguous 1 KB (2 adjacent rows).
__global__ __launch_bounds__(256) void k_nodeB(
    const float* __restrict__ F, const float* __restrict__ A,
    float* __restrict__ B, int N) {
  int t = threadIdx.x;
  int q = t & 31;
  int sub = t >> 5;

  float4 acc[16];
#pragma unroll
  for (int k = 0; k < 16; k++) acc[k] = make_float4(0.f, 0.f, 0.f, 0.f);

  const float4* F4 = (const float4*)F;
  const float4* A4 = (const float4*)A;
  int stride = gridDim.x * 8;
  for (int n = blockIdx.x * 8 + sub; n < N; n += stride) {
    float4 f  = F4[(size_t)n * 32 + q];
    float4 a0 = A4[(size_t)n * 4 + 0];
    float4 a1 = A4[(size_t)n * 4 + 1];
    float4 a2 = A4[(size_t)n * 4 + 2];
    float4 a3 = A4[(size_t)n * 4 + 3];
    float av[16] = {a0.x, a0.y, a0.z, a0.w, a1.x, a1.y, a1.z, a1.w,
                    a2.x, a2.y, a2.z, a2.w, a3.x, a3.y, a3.z, a3.w};
#pragma unroll
    for (int k = 0; k < 16; k++) {
      acc[k].x = fmaf(av[k], f.x, acc[k].x);
      acc[k].y = fmaf(av[k], f.y, acc[k].y);
      acc[k].z = fmaf(av[k], f.z, acc[k].z);
      acc[k].w = fmaf(av[k], f.w, acc[k].w);
    }
  }

  // combine sub pairs within the wave (lanes xor 32)
#pragma unroll
  for (int k = 0; k < 16; k++) {
    acc[k].x += __shfl_xor(acc[k].x, 32, 64);
    acc[k].y += __shfl_xor(acc[k].y, 32, 64);
    acc[k].z += __shfl_xor(acc[k].z, 32, 64);
    acc[k].w += __shfl_xor(acc[k].w, 32, 64);
  }

  __shared__ float red[4][2048];   // 32 KB
  int lane = t & 63, wid = t >> 6;
  if (lane < 32) {
#pragma unroll
    for (int k = 0; k < 16; k++)
      *(float4*)&red[wid][k * 128 + q * 4] = acc[k];
  }
  __syncthreads();
#pragma unroll
  for (int qq = 0; qq < 2; qq++) {
    int base = t * 8 + qq * 4;
    float4 s0 = *(float4*)&red[0][base];
    float4 s1 = *(float4*)&red[1][base];
    float4 s2 = *(float4*)&red[2][base];
    float4 s3 = *(float4*)&red[3][base];
    atomicAdd(&B[base + 0], s0.x + s1.x + s2.x + s3.x);
    atomicAdd(&B[base + 1], s0.y + s1.y + s2.y + s3.y);
    atomicAdd(&B[base + 2], s0.z + s1.z + s2.z + s3.z);
    atomicAdd(&B[base + 3], s0.w + s1.w + s2.w + s3.w);
  }
}

// ---------------------------------------------------------------- k_finalize
// P2[k,c] = (1/cs[k]) * selu(B[k,c]/cs[k]);  loss scalar.
__global__ __launch_bounds__(256) void k_finalize(
    float* __restrict__ ws, float* __restrict__ loss_out, int N) {
  __shared__ float invcs[16];
  int t = threadIdx.x;
  if (t < 16) invcs[t] = 1.0f / ws[WS_CS + t];
  __syncthreads();
  const float* B = ws + WS_B;
  float* P2 = ws + WS_P2;
  const float scale = 1.0507009873554805f;
  const float alpha = 1.6732632423543772f;
#pragma unroll
  for (int idx = t; idx < 2048; idx += 256) {
    int k = idx >> 7;
    float x = B[idx] * invcs[k];
    float s = (x > 0.f) ? scale * x : scale * alpha * expm1f(x);
    P2[idx] = s * invcs[k];
  }
  if (t == 0) {
    float Es = ws[WS_ESUM], tr = ws[WS_TR];
    float m2 = 0.f;
#pragma unroll
    for (int i = 0; i < 16; i++) m2 += ws[WS_M + i] * ws[WS_M + i];
    float spectral = -(tr - m2 / (2.0f * Es)) / (2.0f * Es);
    float coll = 0.f;
    float tgt = (float)N / 16.0f;
#pragma unroll
    for (int i = 0; i < 16; i++) coll += fabsf(ws[WS_CS + i] - tgt);
    coll = coll / (float)N * (4.0f / 3.0f / 2.0f);  // sk/(sk-1)/2, sk=4
    loss_out[0] = spectral + coll;
  }
}

// ---------------------------------------------------------------- k_unpool
// out[n,c] = sum_k A[n,k] * P2[k,c]
__global__ __launch_bounds__(256) void k_unpool(
    const float* __restrict__ A, const float* __restrict__ P2,
    float* __restrict__ out, int N) {
  __shared__ float Ps[2048];
  int t = threadIdx.x;
#pragma unroll
  for (int i = 0; i < 8; i++) Ps[t + 256 * i] = P2[t + 256 * i];
  __syncthreads();
  int c = t & 127;
  int half = t >> 7;
  int pairs = (N + 1) >> 1;
  for (int p = blockIdx.x; p < pairs; p += gridDim.x) {
    int n = p * 2 + half;
    if (n < N) {
      const float4* a4 = (const float4*)(A + (size_t)n * 16);
      float4 a0 = a4[0], a1 = a4[1], a2 = a4[2], a3 = a4[3];
      float s = a0.x * Ps[0 * 128 + c] + a0.y * Ps[1 * 128 + c]
              + a0.z * Ps[2 * 128 + c] + a0.w * Ps[3 * 128 + c]
              + a1.x * Ps[4 * 128 + c] + a1.y * Ps[5 * 128 + c]
              + a1.z * Ps[6 * 128 + c] + a1.w * Ps[7 * 128 + c]
              + a2.x * Ps[8 * 128 + c] + a2.y * Ps[9 * 128 + c]
              + a2.z * Ps[10 * 128 + c] + a2.w * Ps[11 * 128 + c]
              + a3.x * Ps[12 * 128 + c] + a3.y * Ps[13 * 128 + c]
              + a3.z * Ps[14 * 128 + c] + a3.w * Ps[15 * 128 + c];
      out[(size_t)n * 128 + c] = s;
    }
  }
}

// ----------------------------------------------------------------
extern "C" void kernel_launch(void* const* d_in, const int* in_sizes, int n_in,
                              void* d_out, int out_size, void* d_ws, size_t ws_size,
                              hipStream_t stream) {
  const float* F    = (const float*)d_in[0];  // [N,128]
  const int*   erow = (const int*)d_in[1];    // [E]
  const int*   ecol = (const int*)d_in[2];    // [E]
  const float* eval_= (const float*)d_in[3];  // [E]
  const float* W    = (const float*)d_in[4];  // [16,128]
  const float* bias = (const float*)d_in[5];  // [16]

  int N = in_sizes[0] / 128;
  int E = in_sizes[1];

  float* out0 = (float*)d_out;                 // features_pooled [N,128]
  float* A    = out0 + (size_t)N * 128;        // assignments [N,16]
  float* loss = A + (size_t)N * 16;            // scalar
  float* ws   = (float*)d_ws;

  // zero the atomic accumulators: scalars/m/cs + B = (64 + 2048) floats
  hipMemsetAsync(d_ws, 0, (size_t)(WS_B + 2048) * sizeof(float), stream);

  k_assign<<<(N + 255) / 256, 256, 0, stream>>>(F, W, bias, A, ws + WS_CS, N);
  k_edge<<<1024, 256, 0, stream>>>(erow, ecol, eval_, A, ws, E);
  k_nodeB<<<1024, 256, 0, stream>>>(F, A, ws + WS_B, N);
  k_finalize<<<1, 256, 0, stream>>>(ws, loss, N);
  k_unpool<<<1024, 256, 0, stream>>>(A, ws + WS_P2, out0, N);
}

// Round 6
// 278.395 us; speedup vs baseline: 1.5959x; 1.5959x over previous
//
#include <hip/hip_runtime.h>
#include <math.h>

// ws float layout:
//  [0]      E_sum      (written by k_reduce)
//  [1]      tr_gp      (written by k_reduce)
//  [2..17]  m[16]      (written by k_reduce)
//  [18..33] cs[16]     (written by k_reduce)
//  [64..2112)   B[16][128]   (written by k_reduce)
//  [2112..4160) P2[16][128]  (written by k_finalize)
//  [4160..)     per-block partials: cs[GA][16], edge[GE][18], B[GB][2048]
// No atomics anywhere: every region is plain-stored before it is read.

#define WS_ESUM 0
#define WS_TR   1
#define WS_M    2
#define WS_CS   18
#define WS_B    64
#define WS_P2   2112
#define WS_PART 4160

// ---------------------------------------------------------------- k_assign
// A[n,:] = softmax(F[n,:] @ W^T + b); csp[blk][k] = block-partial cs
__global__ __launch_bounds__(256) void k_assign(
    const float* __restrict__ F, const float* __restrict__ W,
    const float* __restrict__ bias, float* __restrict__ A,
    float* __restrict__ csp, int N) {
  __shared__ float Ws[2048];       // fc_w [16][128]
  __shared__ float csred[4][16];
  int t = threadIdx.x;
#pragma unroll
  for (int i = 0; i < 8; i++) Ws[t + 256 * i] = W[t + 256 * i];
  __syncthreads();

  int n = blockIdx.x * 256 + t;
  float a[16];
  if (n < N) {
#pragma unroll
    for (int k = 0; k < 16; k++) a[k] = bias[k];
    const float4* f4 = (const float4*)(F + (size_t)n * 128);
#pragma unroll 4
    for (int i = 0; i < 32; i++) {
      float4 f = f4[i];
#pragma unroll
      for (int k = 0; k < 16; k++) {
        float4 w = *(const float4*)(&Ws[k * 128 + i * 4]);
        a[k] = fmaf(f.x, w.x, a[k]);
        a[k] = fmaf(f.y, w.y, a[k]);
        a[k] = fmaf(f.z, w.z, a[k]);
        a[k] = fmaf(f.w, w.w, a[k]);
      }
    }
    // softmax
    float mx = a[0];
#pragma unroll
    for (int k = 1; k < 16; k++) mx = fmaxf(mx, a[k]);
    float s = 0.f;
#pragma unroll
    for (int k = 0; k < 16; k++) { a[k] = __expf(a[k] - mx); s += a[k]; }
    float inv = 1.0f / s;
#pragma unroll
    for (int k = 0; k < 16; k++) a[k] *= inv;
    float4* o = (float4*)(A + (size_t)n * 16);
    o[0] = make_float4(a[0], a[1], a[2], a[3]);
    o[1] = make_float4(a[4], a[5], a[6], a[7]);
    o[2] = make_float4(a[8], a[9], a[10], a[11]);
    o[3] = make_float4(a[12], a[13], a[14], a[15]);
  } else {
#pragma unroll
    for (int k = 0; k < 16; k++) a[k] = 0.f;
  }

  // cluster-size block partial: wave butterfly -> LDS -> one store
#pragma unroll
  for (int k = 0; k < 16; k++) {
    float v = a[k];
    for (int off = 32; off; off >>= 1) v += __shfl_xor(v, off, 64);
    a[k] = v;
  }
  int lane = t & 63, wid = t >> 6;
  if (lane == 0) {
#pragma unroll
    for (int k = 0; k < 16; k++) csred[wid][k] = a[k];
  }
  __syncthreads();
  if (t < 16)
    csp[(size_t)blockIdx.x * 16 + t] =
        csred[0][t] + csred[1][t] + csred[2][t] + csred[3][t];
}

// ---------------------------------------------------------------- k_edge
// Block partials of: E_sum, tr = sum v*dot(A[r],A[c]), m[k] = sum v*A[c,k]
__global__ __launch_bounds__(256) void k_edge(
    const int* __restrict__ row, const int* __restrict__ col,
    const float* __restrict__ val, const float* __restrict__ A,
    float* __restrict__ ep, int E) {
  float eS = 0.f, tr = 0.f;
  float m[16];
#pragma unroll
  for (int i = 0; i < 16; i++) m[i] = 0.f;

  int tid = blockIdx.x * 256 + threadIdx.x;
  int T = gridDim.x * 256;
  for (int e = tid; e < E; e += T) {
    int r = row[e], c = col[e];
    float v = val[e];
    const float4* Ac4 = (const float4*)(A + (size_t)c * 16);
    const float4* Ar4 = (const float4*)(A + (size_t)r * 16);
    float4 c0 = Ac4[0], c1 = Ac4[1], c2 = Ac4[2], c3 = Ac4[3];
    float4 r0 = Ar4[0], r1 = Ar4[1], r2 = Ar4[2], r3 = Ar4[3];
    eS += v;
    m[0]  = fmaf(v, c0.x, m[0]);  m[1]  = fmaf(v, c0.y, m[1]);
    m[2]  = fmaf(v, c0.z, m[2]);  m[3]  = fmaf(v, c0.w, m[3]);
    m[4]  = fmaf(v, c1.x, m[4]);  m[5]  = fmaf(v, c1.y, m[5]);
    m[6]  = fmaf(v, c1.z, m[6]);  m[7]  = fmaf(v, c1.w, m[7]);
    m[8]  = fmaf(v, c2.x, m[8]);  m[9]  = fmaf(v, c2.y, m[9]);
    m[10] = fmaf(v, c2.z, m[10]); m[11] = fmaf(v, c2.w, m[11]);
    m[12] = fmaf(v, c3.x, m[12]); m[13] = fmaf(v, c3.y, m[13]);
    m[14] = fmaf(v, c3.z, m[14]); m[15] = fmaf(v, c3.w, m[15]);
    float d = r0.x * c0.x + r0.y * c0.y + r0.z * c0.z + r0.w * c0.w
            + r1.x * c1.x + r1.y * c1.y + r1.z * c1.z + r1.w * c1.w
            + r2.x * c2.x + r2.y * c2.y + r2.z * c2.z + r2.w * c2.w
            + r3.x * c3.x + r3.y * c3.y + r3.z * c3.z + r3.w * c3.w;
    tr = fmaf(v, d, tr);
  }

  float vals[18];
  vals[0] = eS; vals[1] = tr;
#pragma unroll
  for (int i = 0; i < 16; i++) vals[2 + i] = m[i];
#pragma unroll
  for (int i = 0; i < 18; i++) {
    float v = vals[i];
    for (int off = 32; off; off >>= 1) v += __shfl_xor(v, off, 64);
    vals[i] = v;
  }
  __shared__ float red[4][18];
  int lane = threadIdx.x & 63, wid = threadIdx.x >> 6;
  if (lane == 0) {
#pragma unroll
    for (int i = 0; i < 18; i++) red[wid][i] = vals[i];
  }
  __syncthreads();
  if (threadIdx.x < 18)
    ep[(size_t)blockIdx.x * 18 + threadIdx.x] =
        red[0][threadIdx.x] + red[1][threadIdx.x] +
        red[2][threadIdx.x] + red[3][threadIdx.x];
}

// ---------------------------------------------------------------- k_nodeB
// Block partials of B[k,c] = sum_n A[n,k]*F[n,c].
// thread: q = t&31 (float4 column), sub = t>>5 (node slot 0..7);
// wave F loads = one contiguous 1 KB.
__global__ __launch_bounds__(256) void k_nodeB(
    const float* __restrict__ F, const float* __restrict__ A,
    float* __restrict__ bp, int N) {
  int t = threadIdx.x;
  int q = t & 31;
  int sub = t >> 5;

  float4 acc[16];
#pragma unroll
  for (int k = 0; k < 16; k++) acc[k] = make_float4(0.f, 0.f, 0.f, 0.f);

  const float4* F4 = (const float4*)F;
  const float4* A4 = (const float4*)A;
  int stride = gridDim.x * 8;
  for (int n = blockIdx.x * 8 + sub; n < N; n += stride) {
    float4 f  = F4[(size_t)n * 32 + q];
    float4 a0 = A4[(size_t)n * 4 + 0];
    float4 a1 = A4[(size_t)n * 4 + 1];
    float4 a2 = A4[(size_t)n * 4 + 2];
    float4 a3 = A4[(size_t)n * 4 + 3];
    float av[16] = {a0.x, a0.y, a0.z, a0.w, a1.x, a1.y, a1.z, a1.w,
                    a2.x, a2.y, a2.z, a2.w, a3.x, a3.y, a3.z, a3.w};
#pragma unroll
    for (int k = 0; k < 16; k++) {
      acc[k].x = fmaf(av[k], f.x, acc[k].x);
      acc[k].y = fmaf(av[k], f.y, acc[k].y);
      acc[k].z = fmaf(av[k], f.z, acc[k].z);
      acc[k].w = fmaf(av[k], f.w, acc[k].w);
    }
  }

  // combine the two node slots sharing q (lanes xor 32)
#pragma unroll
  for (int k = 0; k < 16; k++) {
    acc[k].x += __shfl_xor(acc[k].x, 32, 64);
    acc[k].y += __shfl_xor(acc[k].y, 32, 64);
    acc[k].z += __shfl_xor(acc[k].z, 32, 64);
    acc[k].w += __shfl_xor(acc[k].w, 32, 64);
  }

  __shared__ float red[4][2048];   // 32 KB
  int lane = t & 63, wid = t >> 6;
  if (lane < 32) {
#pragma unroll
    for (int k = 0; k < 16; k++)
      *(float4*)&red[wid][k * 128 + q * 4] = acc[k];
  }
  __syncthreads();
  float* myp = bp + (size_t)blockIdx.x * 2048;
#pragma unroll
  for (int qq = 0; qq < 2; qq++) {
    int base = t * 8 + qq * 4;
    float4 s0 = *(float4*)&red[0][base];
    float4 s1 = *(float4*)&red[1][base];
    float4 s2 = *(float4*)&red[2][base];
    float4 s3 = *(float4*)&red[3][base];
    *(float4*)&myp[base] = make_float4(s0.x + s1.x + s2.x + s3.x,
                                       s0.y + s1.y + s2.y + s3.y,
                                       s0.z + s1.z + s2.z + s3.z,
                                       s0.w + s1.w + s2.w + s3.w);
  }
}

// ---------------------------------------------------------------- k_reduce
// 34 blocks: 0..31 reduce B partials (64 cells each), 32 reduces edge
// scalars, 33 reduces cluster sizes. All reads coalesced.
__global__ __launch_bounds__(256) void k_reduce(
    const float* __restrict__ csp, const float* __restrict__ ep,
    const float* __restrict__ bp, float* __restrict__ ws,
    int GA, int GE, int GB) {
  __shared__ float L[256];
  int t = threadIdx.x;
  int b = blockIdx.x;
  if (b < 32) {
    int cell = b * 64 + (t & 63);
    int seg = t >> 6;
    float s = 0.f;
    for (int g = seg; g < GB; g += 4) s += bp[(size_t)g * 2048 + cell];
    L[t] = s;
    __syncthreads();
    if (t < 64)
      ws[WS_B + b * 64 + t] = L[t] + L[64 + t] + L[128 + t] + L[192 + t];
  } else if (b == 32) {
    int i = t % 18, s = t / 18;
    float v = 0.f;
    if (s < 14) {
      for (int g = s; g < GE; g += 14) v += ep[(size_t)g * 18 + i];
    }
    L[t] = v;
    __syncthreads();
    if (t < 18) {
      float tot = 0.f;
#pragma unroll
      for (int ss = 0; ss < 14; ss++) tot += L[ss * 18 + t];
      ws[t] = tot;                       // E_sum, tr, m[16]
    }
  } else {
    int i = t & 15, s = t >> 4;
    float v = 0.f;
    for (int g = s; g < GA; g += 16) v += csp[(size_t)g * 16 + i];
    L[t] = v;
    __syncthreads();
    if (t < 16) {
      float tot = 0.f;
#pragma unroll
      for (int ss = 0; ss < 16; ss++) tot += L[ss * 16 + t];
      ws[WS_CS + t] = tot;
    }
  }
}

// ---------------------------------------------------------------- k_finalize
// P2[k,c] = (1/cs[k]) * selu(B[k,c]/cs[k]);  loss scalar.
__global__ __launch_bounds__(256) void k_finalize(
    float* __restrict__ ws, float* __restrict__ loss_out, int N) {
  __shared__ float invcs[16];
  int t = threadIdx.x;
  if (t < 16) invcs[t] = 1.0f / ws[WS_CS + t];
  __syncthreads();
  const float* B = ws + WS_B;
  float* P2 = ws + WS_P2;
  const float scale = 1.0507009873554805f;
  const float alpha = 1.6732632423543772f;
#pragma unroll
  for (int idx = t; idx < 2048; idx += 256) {
    int k = idx >> 7;
    float x = B[idx] * invcs[k];
    float s = (x > 0.f) ? scale * x : scale * alpha * expm1f(x);
    P2[idx] = s * invcs[k];
  }
  if (t == 0) {
    float Es = ws[WS_ESUM], tr = ws[WS_TR];
    float m2 = 0.f;
#pragma unroll
    for (int i = 0; i < 16; i++) m2 += ws[WS_M + i] * ws[WS_M + i];
    float spectral = -(tr - m2 / (2.0f * Es)) / (2.0f * Es);
    float coll = 0.f;
    float tgt = (float)N / 16.0f;
#pragma unroll
    for (int i = 0; i < 16; i++) coll += fabsf(ws[WS_CS + i] - tgt);
    coll = coll / (float)N * (4.0f / 3.0f / 2.0f);  // sk/(sk-1)/2, sk=4
    loss_out[0] = spectral + coll;
  }
}

// ---------------------------------------------------------------- k_unpool
// out[n,c] = sum_k A[n,k] * P2[k,c]
__global__ __launch_bounds__(256) void k_unpool(
    const float* __restrict__ A, const float* __restrict__ P2,
    float* __restrict__ out, int N) {
  __shared__ float Ps[2048];
  int t = threadIdx.x;
#pragma unroll
  for (int i = 0; i < 8; i++) Ps[t + 256 * i] = P2[t + 256 * i];
  __syncthreads();
  int c = t & 127;
  int half = t >> 7;
  int pairs = (N + 1) >> 1;
  for (int p = blockIdx.x; p < pairs; p += gridDim.x) {
    int n = p * 2 + half;
    if (n < N) {
      const float4* a4 = (const float4*)(A + (size_t)n * 16);
      float4 a0 = a4[0], a1 = a4[1], a2 = a4[2], a3 = a4[3];
      float s = a0.x * Ps[0 * 128 + c] + a0.y * Ps[1 * 128 + c]
              + a0.z * Ps[2 * 128 + c] + a0.w * Ps[3 * 128 + c]
              + a1.x * Ps[4 * 128 + c] + a1.y * Ps[5 * 128 + c]
              + a1.z * Ps[6 * 128 + c] + a1.w * Ps[7 * 128 + c]
              + a2.x * Ps[8 * 128 + c] + a2.y * Ps[9 * 128 + c]
              + a2.z * Ps[10 * 128 + c] + a2.w * Ps[11 * 128 + c]
              + a3.x * Ps[12 * 128 + c] + a3.y * Ps[13 * 128 + c]
              + a3.z * Ps[14 * 128 + c] + a3.w * Ps[15 * 128 + c];
      out[(size_t)n * 128 + c] = s;
    }
  }
}

// ----------------------------------------------------------------
extern "C" void kernel_launch(void* const* d_in, const int* in_sizes, int n_in,
                              void* d_out, int out_size, void* d_ws, size_t ws_size,
                              hipStream_t stream) {
  const float* F    = (const float*)d_in[0];  // [N,128]
  const int*   erow = (const int*)d_in[1];    // [E]
  const int*   ecol = (const int*)d_in[2];    // [E]
  const float* eval_= (const float*)d_in[3];  // [E]
  const float* W    = (const float*)d_in[4];  // [16,128]
  const float* bias = (const float*)d_in[5];  // [16]

  int N = in_sizes[0] / 128;
  int E = in_sizes[1];

  float* out0 = (float*)d_out;                 // features_pooled [N,128]
  float* A    = out0 + (size_t)N * 128;        // assignments [N,16]
  float* loss = A + (size_t)N * 16;            // scalar
  float* ws   = (float*)d_ws;

  int GA = (N + 255) / 256;                    // k_assign grid (391)
  int GE = 1024;                               // k_edge grid
  int GB = 256;                                // k_nodeB grid

  // fit partial buffers into ws (adaptive, in case ws is small)
  size_t availf = ws_size / 4;
  size_t off_csp = WS_PART;
  size_t off_ep  = off_csp + (size_t)GA * 16;
  size_t need = off_ep + (size_t)GE * 18 + (size_t)GB * 2048;
  while (need > availf && GB > 1) { GB >>= 1; need = off_ep + (size_t)GE * 18 + (size_t)GB * 2048; }
  while (need > availf && GE > 1) { GE >>= 1; need = off_ep + (size_t)GE * 18 + (size_t)GB * 2048; }
  size_t off_bp = off_ep + (size_t)GE * 18;

  float* csp = ws + off_csp;
  float* ep  = ws + off_ep;
  float* bp  = ws + off_bp;

  k_assign<<<GA, 256, 0, stream>>>(F, W, bias, A, csp, N);
  k_edge<<<GE, 256, 0, stream>>>(erow, ecol, eval_, A, ep, E);
  k_nodeB<<<GB, 256, 0, stream>>>(F, A, bp, N);
  k_reduce<<<34, 256, 0, stream>>>(csp, ep, bp, ws, GA, GE, GB);
  k_finalize<<<1, 256, 0, stream>>>(ws, loss, N);
  k_unpool<<<1024, 256, 0, stream>>>(A, ws + WS_P2, out0, N);
}